// Round 1
// baseline (5499.939 us; speedup 1.0000x reference)
//
#include <hip/hip_runtime.h>
#include <float.h>

#define BB   8
#define NN   4096
#define SS   2048
#define KK   16
#define MID  32
#define COUT 64
#define CAT  67            // 3 + 64
#define M1   (BB*NN)       // 32768
#define M2   (BB*SS)       // 16384
#define EPSB 1e-5f

// ---- workspace layout (float offsets) ----
#define WS_RED1  0                       // 12 floats  (Sx[3], C[6])
#define WS_RED2  16                      // 128 floats (sum[64], sumsq[64])
#define WS_A1C1  160                     // 64 floats
#define WS_A2C2  256                     // 128 floats
#define WS_FPS   512                     // 16384 ints
#define WS_FEATS (512 + 16384)           // 32768*64 floats
#define WS_POOL  (WS_FEATS + M1*COUT)    // 16384*67 floats

// ---------------- K1: input moments for BN1 stats ----------------
__global__ __launch_bounds__(256) void k1_stats(const float* __restrict__ xin,
                                                float* __restrict__ ws) {
    int t = blockIdx.x * 256 + threadIdx.x;
    float r[9];
#pragma unroll
    for (int q = 0; q < 9; q++) r[q] = 0.f;
    for (int p = t; p < M1; p += 64 * 256) {
        float x0 = xin[3 * p], x1 = xin[3 * p + 1], x2 = xin[3 * p + 2];
        r[0] += x0; r[1] += x1; r[2] += x2;
        r[3] = fmaf(x0, x0, r[3]); r[4] = fmaf(x0, x1, r[4]); r[5] = fmaf(x0, x2, r[5]);
        r[6] = fmaf(x1, x1, r[6]); r[7] = fmaf(x1, x2, r[7]); r[8] = fmaf(x2, x2, r[8]);
    }
#pragma unroll
    for (int m = 32; m; m >>= 1) {
#pragma unroll
        for (int q = 0; q < 9; q++) r[q] += __shfl_down(r[q], m, 64);
    }
    if ((threadIdx.x & 63) == 0) {
#pragma unroll
        for (int q = 0; q < 9; q++) atomicAdd(ws + WS_RED1 + q, r[q]);
    }
}

// ---------------- K2: derive BN1 scale/shift per channel ----------------
__global__ void k2_prep(const float* __restrict__ W1, const float* __restrict__ b1,
                        const float* __restrict__ g1, const float* __restrict__ be1,
                        float* __restrict__ ws) {
    int o = threadIdx.x;
    if (o >= MID) return;
    const float* r = ws + WS_RED1;
    float S0 = r[0], S1 = r[1], S2 = r[2];
    float C00 = r[3], C01 = r[4], C02 = r[5], C11 = r[6], C12 = r[7], C22 = r[8];
    float w0 = W1[3 * o], w1 = W1[3 * o + 1], w2 = W1[3 * o + 2];
    float invM = 1.f / (float)M1;
    float wS = w0 * S0 + w1 * S1 + w2 * S2;
    float mean = wS * invM + b1[o];
    float wCw = w0 * w0 * C00 + w1 * w1 * C11 + w2 * w2 * C22 +
                2.f * (w0 * w1 * C01 + w0 * w2 * C02 + w1 * w2 * C12);
    float ey2 = (wCw + 2.f * b1[o] * wS) * invM + b1[o] * b1[o];
    float var = ey2 - mean * mean;
    float a = g1[o] * rsqrtf(var + EPSB);
    ws[WS_A1C1 + o] = a;
    ws[WS_A1C1 + MID + o] = be1[o] - mean * a;
}

// ---------------- K3: feats = conv2(relu(bn(conv1(x)))) ----------------
__global__ __launch_bounds__(256) void k3_feats(const float* __restrict__ xin,
                                                const float* __restrict__ W1,
                                                const float* __restrict__ b1,
                                                const float* __restrict__ W2,
                                                const float* __restrict__ b2,
                                                float* __restrict__ ws) {
    __shared__ float W1s[96], b1s[32], abv[64], W2s[2048], b2s[64];
    int tid = threadIdx.x;
    for (int j = tid; j < 96; j += 256) W1s[j] = W1[j];
    if (tid < 32) b1s[tid] = b1[tid];
    if (tid < 64) { abv[tid] = ws[WS_A1C1 + tid]; b2s[tid] = b2[tid]; }
    for (int j = tid; j < 2048; j += 256) W2s[j] = W2[j];
    __syncthreads();
    int p = blockIdx.x * 256 + tid;
    float x0 = xin[3 * p], x1 = xin[3 * p + 1], x2 = xin[3 * p + 2];
    float h[MID];
#pragma unroll
    for (int o = 0; o < MID; o++) {
        float y = fmaf(W1s[3 * o + 2], x2, fmaf(W1s[3 * o + 1], x1, fmaf(W1s[3 * o], x0, b1s[o])));
        h[o] = fmaxf(0.f, fmaf(abv[o], y, abv[MID + o]));
    }
    float* fo = ws + WS_FEATS + (size_t)p * COUT;
#pragma unroll
    for (int j = 0; j < COUT; j += 4) {
        float a0 = b2s[j], a1v = b2s[j + 1], a2v = b2s[j + 2], a3v = b2s[j + 3];
#pragma unroll
        for (int o = 0; o < MID; o++) {
            float hv = h[o];
            a0  = fmaf(W2s[(j)     * MID + o], hv, a0);
            a1v = fmaf(W2s[(j + 1) * MID + o], hv, a1v);
            a2v = fmaf(W2s[(j + 2) * MID + o], hv, a2v);
            a3v = fmaf(W2s[(j + 3) * MID + o], hv, a3v);
        }
        *(float4*)(fo + j) = make_float4(a0, a1v, a2v, a3v);
    }
}

// ---------------- K4: farthest point sampling (one block per batch) ----------------
__global__ __launch_bounds__(256) void k4_fps(const float* __restrict__ xin,
                                              float* __restrict__ ws) {
    __shared__ float2 Pxy[NN];      // 32 KB
    __shared__ float  Pz[NN];       // 16 KB
    __shared__ float  rv[2][4];
    __shared__ int    ri[2][4];
    int b = blockIdx.x, tid = threadIdx.x;
    const float* xb = xin + (size_t)b * NN * 3;
    for (int j = tid; j < NN; j += 256) {
        Pxy[j] = make_float2(xb[3 * j], xb[3 * j + 1]);
        Pz[j] = xb[3 * j + 2];
    }
    int* fidx = (int*)(ws + WS_FPS) + b * SS;
    if (tid == 0) fidx[0] = 0;
    float dist[16];
#pragma unroll
    for (int k = 0; k < 16; k++) dist[k] = FLT_MAX;
    __syncthreads();
    float cx = Pxy[0].x, cy = Pxy[0].y, cz = Pz[0];
    for (int t = 1; t < SS; t++) {
        float bv = -1.f; int bi = 0;
#pragma unroll
        for (int k = 0; k < 16; k++) {
            int i = tid + (k << 8);
            float dx = Pxy[i].x - cx, dy = Pxy[i].y - cy, dz = Pz[i] - cz;
            float d = fmaf(dz, dz, fmaf(dy, dy, dx * dx));
            float nd = fminf(dist[k], d);
            dist[k] = nd;
            bool bt = nd > bv;           // strict >  => lowest index wins ties
            bv = bt ? nd : bv; bi = bt ? i : bi;
        }
#pragma unroll
        for (int m = 32; m; m >>= 1) {
            float ov = __shfl_xor(bv, m, 64);
            int   oi = __shfl_xor(bi, m, 64);
            if (ov > bv || (ov == bv && oi < bi)) { bv = ov; bi = oi; }
        }
        int par = t & 1;
        if ((tid & 63) == 0) { rv[par][tid >> 6] = bv; ri[par][tid >> 6] = bi; }
        __syncthreads();
        bv = rv[par][0]; bi = ri[par][0];
#pragma unroll
        for (int w = 1; w < 4; w++) {
            float ov = rv[par][w]; int oi = ri[par][w];
            if (ov > bv || (ov == bv && oi < bi)) { bv = ov; bi = oi; }
        }
        cx = Pxy[bi].x; cy = Pxy[bi].y; cz = Pz[bi];
        if (tid == 0) fidx[t] = bi;
    }
}

// ---------------- K5: 16-NN + group + maxpool (thread per centroid) ----------------
__global__ __launch_bounds__(256) void k5_group(const float* __restrict__ xin,
                                                float* __restrict__ ws) {
    __shared__ float4 Pq[NN];       // 64 KB: x,y,z,|p|^2
    int blk = blockIdx.x, tid = threadIdx.x;
    int b = blk >> 3;
    const float* xb = xin + (size_t)b * NN * 3;
    for (int j = tid; j < NN; j += 256) {
        float x = xb[3 * j], y = xb[3 * j + 1], z = xb[3 * j + 2];
        Pq[j] = make_float4(x, y, z, (x * x + y * y) + z * z);
    }
    __syncthreads();
    int s = (blk & 7) * 256 + tid;
    int sg = b * SS + s;
    const int* fidx = (const int*)(ws + WS_FPS);
    int ci = fidx[sg];
    float4 c = Pq[ci];
    float an = c.w;
    float dv[16]; int di[16];
#pragma unroll
    for (int j = 0; j < 16; j++) { dv[j] = FLT_MAX; di[j] = 0x7fffffff; }
    float cmax = FLT_MAX; int cpos = 0, cidx = 0x7fffffff;
    for (int n = 0; n < NN; n++) {
        float4 q = Pq[n];
        float dot = fmaf(c.z, q.z, fmaf(c.y, q.y, c.x * q.x));
        float dd = (an + q.w) - 2.f * dot;
        if (dd < cmax) {                  // strict <  => stored (lower idx) wins ties
#pragma unroll
            for (int j = 0; j < 16; j++) {
                bool sel = (j == cpos);
                dv[j] = sel ? dd : dv[j];
                di[j] = sel ? n : di[j];
            }
            cmax = dv[0]; cidx = di[0]; cpos = 0;
#pragma unroll
            for (int j = 1; j < 16; j++) {   // evict max; tie -> larger index
                bool bt = (dv[j] > cmax) || ((dv[j] == cmax) && (di[j] > cidx));
                cmax = bt ? dv[j] : cmax; cidx = bt ? di[j] : cidx; cpos = bt ? j : cpos;
            }
        }
    }
    // pooling over the 16 neighbors
    const float* feats = ws + WS_FEATS;
    float rx = -FLT_MAX, ry = -FLT_MAX, rz = -FLT_MAX;
    float4 acc[16];
#pragma unroll
    for (int m = 0; m < 16; m++) acc[m] = make_float4(-FLT_MAX, -FLT_MAX, -FLT_MAX, -FLT_MAX);
    for (int k = 0; k < 16; k++) {
        int i = di[k];
        float4 q = Pq[i];
        rx = fmaxf(rx, q.x - c.x); ry = fmaxf(ry, q.y - c.y); rz = fmaxf(rz, q.z - c.z);
        const float4* fp = (const float4*)(feats + (size_t)(b * NN + i) * COUT);
#pragma unroll
        for (int m = 0; m < 16; m++) {
            float4 v = fp[m];
            acc[m].x = fmaxf(acc[m].x, v.x); acc[m].y = fmaxf(acc[m].y, v.y);
            acc[m].z = fmaxf(acc[m].z, v.z); acc[m].w = fmaxf(acc[m].w, v.w);
        }
    }
    float* po = ws + WS_POOL + (size_t)sg * CAT;
    po[0] = rx; po[1] = ry; po[2] = rz;
#pragma unroll
    for (int m = 0; m < 16; m++) {
        po[3 + 4 * m] = acc[m].x; po[4 + 4 * m] = acc[m].y;
        po[5 + 4 * m] = acc[m].z; po[6 + 4 * m] = acc[m].w;
    }
}

// ---------------- K6: BN2 stats over conv3 output ----------------
__global__ __launch_bounds__(256) void k6_stats2(const float* __restrict__ W3,
                                                 const float* __restrict__ b3,
                                                 float* __restrict__ ws) {
    __shared__ float W3s[64 * CAT];
    __shared__ float b3s[64];
    __shared__ float ps[128];
    int tid = threadIdx.x;
    for (int j = tid; j < 64 * CAT; j += 256) W3s[j] = W3[j];
    if (tid < 64) b3s[tid] = b3[tid];
    if (tid < 128) ps[tid] = 0.f;
    __syncthreads();
    int c = tid & 63, g = tid >> 6;
    const float* pool = ws + WS_POOL;
    float sum = 0.f, sq = 0.f;
    for (int m = 0; m < 64; m++) {
        int pt = blockIdx.x * 256 + g * 64 + m;
        const float* row = pool + (size_t)pt * CAT;
        float y = b3s[c];
        for (int j = 0; j < CAT; j++) y = fmaf(W3s[c * CAT + j], row[j], y);
        sum += y; sq = fmaf(y, y, sq);
    }
    atomicAdd(&ps[c], sum);
    atomicAdd(&ps[64 + c], sq);
    __syncthreads();
    if (tid < 128) atomicAdd(ws + WS_RED2 + tid, ps[tid]);
}

// ---------------- K7: derive BN2 scale/shift ----------------
__global__ void k7_prep2(const float* __restrict__ g2, const float* __restrict__ be2,
                         float* __restrict__ ws) {
    int c = threadIdx.x;
    if (c >= 64) return;
    float inv = 1.f / (float)M2;
    float mean = ws[WS_RED2 + c] * inv;
    float var = ws[WS_RED2 + 64 + c] * inv - mean * mean;
    float a = g2[c] * rsqrtf(var + EPSB);
    ws[WS_A2C2 + c] = a;
    ws[WS_A2C2 + 64 + c] = be2[c] - mean * a;
}

// ---------------- K8: out = conv4(relu(bn2(conv3(pooled)))) ----------------
__global__ __launch_bounds__(256) void k8_out(const float* __restrict__ W3,
                                              const float* __restrict__ b3,
                                              const float* __restrict__ W4,
                                              const float* __restrict__ b4,
                                              const float* __restrict__ ws,
                                              float* __restrict__ out) {
    __shared__ float W3s[64 * CAT], W4s[64 * 64], b3s[64], b4s[64], ab[128];
    int tid = threadIdx.x;
    for (int j = tid; j < 64 * CAT; j += 256) W3s[j] = W3[j];
    for (int j = tid; j < 4096; j += 256) W4s[j] = W4[j];
    if (tid < 64) { b3s[tid] = b3[tid]; b4s[tid] = b4[tid]; }
    if (tid < 128) ab[tid] = ws[WS_A2C2 + tid];
    __syncthreads();
    int pt = blockIdx.x * 256 + tid;
    const float* row = ws + WS_POOL + (size_t)pt * CAT;
    float p[CAT];
#pragma unroll
    for (int j = 0; j < CAT; j++) p[j] = row[j];
    float h[64];
    for (int c = 0; c < 64; c++) {
        float y = b3s[c];
#pragma unroll
        for (int j = 0; j < CAT; j++) y = fmaf(W3s[c * CAT + j], p[j], y);
        h[c] = fmaxf(0.f, fmaf(ab[c], y, ab[64 + c]));
    }
    float* op = out + (size_t)pt * 64;
    for (int o = 0; o < 64; o += 4) {
        float a0 = b4s[o], a1v = b4s[o + 1], a2v = b4s[o + 2], a3v = b4s[o + 3];
#pragma unroll
        for (int c = 0; c < 64; c++) {
            float hv = h[c];
            a0  = fmaf(W4s[(o)     * 64 + c], hv, a0);
            a1v = fmaf(W4s[(o + 1) * 64 + c], hv, a1v);
            a2v = fmaf(W4s[(o + 2) * 64 + c], hv, a2v);
            a3v = fmaf(W4s[(o + 3) * 64 + c], hv, a3v);
        }
        *(float4*)(op + o) = make_float4(a0, a1v, a2v, a3v);
    }
}

extern "C" void kernel_launch(void* const* d_in, const int* in_sizes, int n_in,
                              void* d_out, int out_size, void* d_ws, size_t ws_size,
                              hipStream_t stream) {
    (void)in_sizes; (void)n_in; (void)out_size; (void)ws_size;
    const float* xin = (const float*)d_in[0];
    const float* W1  = (const float*)d_in[1];
    const float* b1  = (const float*)d_in[2];
    const float* g1  = (const float*)d_in[3];
    const float* be1 = (const float*)d_in[4];
    const float* W2  = (const float*)d_in[5];
    const float* b2  = (const float*)d_in[6];
    const float* W3  = (const float*)d_in[7];
    const float* b3  = (const float*)d_in[8];
    const float* g2  = (const float*)d_in[9];
    const float* be2 = (const float*)d_in[10];
    const float* W4  = (const float*)d_in[11];
    const float* b4  = (const float*)d_in[12];
    float* ws = (float*)d_ws;
    float* out = (float*)d_out;

    hipMemsetAsync(d_ws, 0, (WS_RED2 + 128) * sizeof(float), stream);
    hipLaunchKernelGGL(k1_stats,  dim3(64),  dim3(256), 0, stream, xin, ws);
    hipLaunchKernelGGL(k2_prep,   dim3(1),   dim3(32),  0, stream, W1, b1, g1, be1, ws);
    hipLaunchKernelGGL(k3_feats,  dim3(128), dim3(256), 0, stream, xin, W1, b1, W2, b2, ws);
    hipLaunchKernelGGL(k4_fps,    dim3(8),   dim3(256), 0, stream, xin, ws);
    hipLaunchKernelGGL(k5_group,  dim3(64),  dim3(256), 0, stream, xin, ws);
    hipLaunchKernelGGL(k6_stats2, dim3(64),  dim3(256), 0, stream, W3, b3, ws);
    hipLaunchKernelGGL(k7_prep2,  dim3(1),   dim3(64),  0, stream, g2, be2, ws);
    hipLaunchKernelGGL(k8_out,    dim3(64),  dim3(256), 0, stream, W3, b3, W4, b4, ws, out);
}

// Round 2
// 4180.009 us; speedup vs baseline: 1.3158x; 1.3158x over previous
//
#include <hip/hip_runtime.h>
#include <float.h>

#define BB   8
#define NN   4096
#define SS   2048
#define KK   16
#define MID  32
#define COUT 64
#define CAT  67            // 3 + 64
#define M1   (BB*NN)       // 32768
#define M2   (BB*SS)       // 16384
#define EPSB 1e-5f

// ---- workspace layout (float offsets) ----
#define WS_RED1  0                       // 12 floats  (Sx[3], C[6])
#define WS_RED2  16                      // 128 floats (sum[64], sumsq[64])
#define WS_A1C1  160                     // 64 floats
#define WS_A2C2  256                     // 128 floats
#define WS_FPS   512                     // 16384 ints
#define WS_FEATS (512 + 16384)           // 32768*64 floats
#define WS_POOL  (WS_FEATS + M1*COUT)    // 16384*67 floats

// ---------------- K1: input moments for BN1 stats ----------------
__global__ __launch_bounds__(256) void k1_stats(const float* __restrict__ xin,
                                                float* __restrict__ ws) {
    int t = blockIdx.x * 256 + threadIdx.x;
    float r[9];
#pragma unroll
    for (int q = 0; q < 9; q++) r[q] = 0.f;
    for (int p = t; p < M1; p += 64 * 256) {
        float x0 = xin[3 * p], x1 = xin[3 * p + 1], x2 = xin[3 * p + 2];
        r[0] += x0; r[1] += x1; r[2] += x2;
        r[3] = fmaf(x0, x0, r[3]); r[4] = fmaf(x0, x1, r[4]); r[5] = fmaf(x0, x2, r[5]);
        r[6] = fmaf(x1, x1, r[6]); r[7] = fmaf(x1, x2, r[7]); r[8] = fmaf(x2, x2, r[8]);
    }
#pragma unroll
    for (int m = 32; m; m >>= 1) {
#pragma unroll
        for (int q = 0; q < 9; q++) r[q] += __shfl_down(r[q], m, 64);
    }
    if ((threadIdx.x & 63) == 0) {
#pragma unroll
        for (int q = 0; q < 9; q++) atomicAdd(ws + WS_RED1 + q, r[q]);
    }
}

// ---------------- K2: derive BN1 scale/shift per channel ----------------
__global__ void k2_prep(const float* __restrict__ W1, const float* __restrict__ b1,
                        const float* __restrict__ g1, const float* __restrict__ be1,
                        float* __restrict__ ws) {
    int o = threadIdx.x;
    if (o >= MID) return;
    const float* r = ws + WS_RED1;
    float S0 = r[0], S1 = r[1], S2 = r[2];
    float C00 = r[3], C01 = r[4], C02 = r[5], C11 = r[6], C12 = r[7], C22 = r[8];
    float w0 = W1[3 * o], w1 = W1[3 * o + 1], w2 = W1[3 * o + 2];
    float invM = 1.f / (float)M1;
    float wS = w0 * S0 + w1 * S1 + w2 * S2;
    float mean = wS * invM + b1[o];
    float wCw = w0 * w0 * C00 + w1 * w1 * C11 + w2 * w2 * C22 +
                2.f * (w0 * w1 * C01 + w0 * w2 * C02 + w1 * w2 * C12);
    float ey2 = (wCw + 2.f * b1[o] * wS) * invM + b1[o] * b1[o];
    float var = ey2 - mean * mean;
    float a = g1[o] * rsqrtf(var + EPSB);
    ws[WS_A1C1 + o] = a;
    ws[WS_A1C1 + MID + o] = be1[o] - mean * a;
}

// ---------------- K3: feats = conv2(relu(bn(conv1(x)))) ----------------
__global__ __launch_bounds__(256) void k3_feats(const float* __restrict__ xin,
                                                const float* __restrict__ W1,
                                                const float* __restrict__ b1,
                                                const float* __restrict__ W2,
                                                const float* __restrict__ b2,
                                                float* __restrict__ ws) {
    __shared__ float W1s[96], b1s[32], abv[64], W2s[2048], b2s[64];
    int tid = threadIdx.x;
    for (int j = tid; j < 96; j += 256) W1s[j] = W1[j];
    if (tid < 32) b1s[tid] = b1[tid];
    if (tid < 64) { abv[tid] = ws[WS_A1C1 + tid]; b2s[tid] = b2[tid]; }
    for (int j = tid; j < 2048; j += 256) W2s[j] = W2[j];
    __syncthreads();
    int p = blockIdx.x * 256 + tid;
    float x0 = xin[3 * p], x1 = xin[3 * p + 1], x2 = xin[3 * p + 2];
    float h[MID];
#pragma unroll
    for (int o = 0; o < MID; o++) {
        float y = fmaf(W1s[3 * o + 2], x2, fmaf(W1s[3 * o + 1], x1, fmaf(W1s[3 * o], x0, b1s[o])));
        h[o] = fmaxf(0.f, fmaf(abv[o], y, abv[MID + o]));
    }
    float* fo = ws + WS_FEATS + (size_t)p * COUT;
#pragma unroll
    for (int j = 0; j < COUT; j += 4) {
        float a0 = b2s[j], a1v = b2s[j + 1], a2v = b2s[j + 2], a3v = b2s[j + 3];
#pragma unroll
        for (int o = 0; o < MID; o++) {
            float hv = h[o];
            a0  = fmaf(W2s[(j)     * MID + o], hv, a0);
            a1v = fmaf(W2s[(j + 1) * MID + o], hv, a1v);
            a2v = fmaf(W2s[(j + 2) * MID + o], hv, a2v);
            a3v = fmaf(W2s[(j + 3) * MID + o], hv, a3v);
        }
        *(float4*)(fo + j) = make_float4(a0, a1v, a2v, a3v);
    }
}

// ---------------- K4: FPS — coords in registers, 1 barrier/iter ----------------
__global__ __launch_bounds__(512) void k4_fps(const float* __restrict__ xin,
                                              float* __restrict__ ws) {
    __shared__ float4 Pc[NN];       // 64 KB (centroid broadcast lookup)
    __shared__ float  sv[2][8];
    __shared__ int    si[2][8];
    int b = blockIdx.x, tid = threadIdx.x;
    const float* xb = xin + (size_t)b * NN * 3;
    float px[8], py[8], pz[8], dist[8];
#pragma unroll
    for (int k = 0; k < 8; k++) {
        int i = tid + (k << 9);
        float x = xb[3 * i], y = xb[3 * i + 1], z = xb[3 * i + 2];
        px[k] = x; py[k] = y; pz[k] = z; dist[k] = FLT_MAX;
        Pc[i] = make_float4(x, y, z, 0.f);
    }
    int* fidx = (int*)(ws + WS_FPS) + b * SS;
    if (tid == 0) fidx[0] = 0;
    __syncthreads();
    float4 c0 = Pc[0];
    float cx = c0.x, cy = c0.y, cz = c0.z;
    int wid = tid >> 6, lane = tid & 63;
    for (int t = 1; t < SS; t++) {
        float bv = -1.f; int bi = 0;
#pragma unroll
        for (int k = 0; k < 8; k++) {
            float dx = px[k] - cx, dy = py[k] - cy, dz = pz[k] - cz;
            float d = fmaf(dz, dz, fmaf(dy, dy, dx * dx));
            float nd = fminf(dist[k], d);
            dist[k] = nd;
            bool bt = nd > bv;              // strict > + ascending k => lowest idx wins
            bv = bt ? nd : bv; bi = bt ? (tid + (k << 9)) : bi;
        }
#pragma unroll
        for (int m = 32; m; m >>= 1) {
            float ov = __shfl_xor(bv, m, 64);
            int   oi = __shfl_xor(bi, m, 64);
            if (ov > bv || (ov == bv && oi < bi)) { bv = ov; bi = oi; }
        }
        int par = t & 1;
        if (lane == 0) { sv[par][wid] = bv; si[par][wid] = bi; }
        __syncthreads();
        bv = sv[par][0]; bi = si[par][0];
#pragma unroll
        for (int w = 1; w < 8; w++) {
            float ov = sv[par][w]; int oi = si[par][w];
            if (ov > bv || (ov == bv && oi < bi)) { bv = ov; bi = oi; }
        }
        float4 cc = Pc[bi];
        cx = cc.x; cy = cc.y; cz = cc.z;
        if (tid == 0) fidx[t] = bi;
    }
}

// ---------------- K5: 16-NN + group + maxpool (4 lanes per centroid) ----------------
// 256 blocks; block handles 64 centroids of one batch. Phase 1: each of 4 lanes
// scans a 1024-candidate chunk keeping its exact top-16 (lexicographic (d,idx)).
// Phase 2: 64->16 merge per centroid. Phase 3: 4 lanes cooperate on maxpool.
__global__ __launch_bounds__(256) void k5_group(const float* __restrict__ xin,
                                                float* __restrict__ ws) {
    __shared__ float4 Pq[NN];            // 64 KB: x,y,z,|p|^2
    __shared__ float2 cand[64][65];      // 33.3 KB (pad 65 to break bank stride)
    __shared__ int    fin[64][16];       // 4 KB
    int blk = blockIdx.x, tid = threadIdx.x;
    int b = blk >> 5;                    // 32 blocks per batch
    const float* xb = xin + (size_t)b * NN * 3;
    for (int j = tid; j < NN; j += 256) {
        float x = xb[3 * j], y = xb[3 * j + 1], z = xb[3 * j + 2];
        Pq[j] = make_float4(x, y, z, (x * x + y * y) + z * z);
    }
    __syncthreads();
    int cl = tid >> 2, q = tid & 3;
    int sg = blk * 64 + cl;              // global centroid id
    const int* fidx = (const int*)(ws + WS_FPS);
    int ci = fidx[sg];
    float4 c = Pq[ci];
    float an = c.w;
    float dv[16]; int di[16];
#pragma unroll
    for (int j = 0; j < 16; j++) { dv[j] = FLT_MAX; di[j] = 0x7fffffff; }
    float cmax = FLT_MAX; int cpos = 0, cidx = 0x7fffffff;
    int nbase = q << 10;
    for (int n0 = 0; n0 < 1024; n0++) {
        int n = nbase + n0;
        float4 qq = Pq[n];
        float dot = fmaf(c.z, qq.z, fmaf(c.y, qq.y, c.x * qq.x));
        float dd = (an + qq.w) - 2.f * dot;
        if (dd < cmax) {                 // ascending n within chunk => strict < exact
#pragma unroll
            for (int j = 0; j < 16; j++) {
                bool sel = (j == cpos);
                dv[j] = sel ? dd : dv[j];
                di[j] = sel ? n : di[j];
            }
            cmax = dv[0]; cidx = di[0]; cpos = 0;
#pragma unroll
            for (int j = 1; j < 16; j++) {
                bool bt = (dv[j] > cmax) || ((dv[j] == cmax) && (di[j] > cidx));
                cmax = bt ? dv[j] : cmax; cidx = bt ? di[j] : cidx; cpos = bt ? j : cpos;
            }
        }
    }
#pragma unroll
    for (int j = 0; j < 16; j++)
        cand[cl][q * 16 + j] = make_float2(dv[j], __int_as_float(di[j]));
    __syncthreads();
    if (tid < 64) {                      // phase 2: merge 64 -> 16
        float mv[16]; int mi[16];
#pragma unroll
        for (int j = 0; j < 16; j++) { mv[j] = FLT_MAX; mi[j] = 0x7fffffff; }
        float mx = FLT_MAX; int mp = 0, mxi = 0x7fffffff;
        for (int k = 0; k < 64; k++) {
            float2 e = cand[tid][k];
            float d = e.x; int i = __float_as_int(e.y);
            if (d < mx || (d == mx && i < mxi)) {   // lexicographic entry test
#pragma unroll
                for (int j = 0; j < 16; j++) {
                    bool sel = (j == mp);
                    mv[j] = sel ? d : mv[j];
                    mi[j] = sel ? i : mi[j];
                }
                mx = mv[0]; mxi = mi[0]; mp = 0;
#pragma unroll
                for (int j = 1; j < 16; j++) {
                    bool bt = (mv[j] > mx) || ((mv[j] == mx) && (mi[j] > mxi));
                    mx = bt ? mv[j] : mx; mxi = bt ? mi[j] : mxi; mp = bt ? j : mp;
                }
            }
        }
#pragma unroll
        for (int j = 0; j < 16; j++) fin[tid][j] = mi[j];
    }
    __syncthreads();
    // phase 3: pooling — lane q handles 16 of the 64 feat channels
    int idxs[16];
#pragma unroll
    for (int j = 0; j < 16; j++) idxs[j] = fin[cl][j];
    const float* feats = ws + WS_FEATS + (size_t)b * NN * COUT;
    float4 acc[4];
#pragma unroll
    for (int m = 0; m < 4; m++) acc[m] = make_float4(-FLT_MAX, -FLT_MAX, -FLT_MAX, -FLT_MAX);
#pragma unroll 4
    for (int k = 0; k < 16; k++) {
        const float4* fp = (const float4*)(feats + (size_t)idxs[k] * COUT) + q * 4;
#pragma unroll
        for (int m = 0; m < 4; m++) {
            float4 v = fp[m];
            acc[m].x = fmaxf(acc[m].x, v.x); acc[m].y = fmaxf(acc[m].y, v.y);
            acc[m].z = fmaxf(acc[m].z, v.z); acc[m].w = fmaxf(acc[m].w, v.w);
        }
    }
    float* po = ws + WS_POOL + (size_t)sg * CAT;
#pragma unroll
    for (int m = 0; m < 4; m++) {
        int base = 3 + q * 16 + m * 4;
        po[base] = acc[m].x; po[base + 1] = acc[m].y;
        po[base + 2] = acc[m].z; po[base + 3] = acc[m].w;
    }
    if (q == 0) {
        float rx = -FLT_MAX, ry = -FLT_MAX, rz = -FLT_MAX;
#pragma unroll
        for (int k = 0; k < 16; k++) {
            float4 p = Pq[idxs[k]];
            rx = fmaxf(rx, p.x - c.x); ry = fmaxf(ry, p.y - c.y); rz = fmaxf(rz, p.z - c.z);
        }
        po[0] = rx; po[1] = ry; po[2] = rz;
    }
}

// ---------------- K6: BN2 stats over conv3 output ----------------
__global__ __launch_bounds__(256) void k6_stats2(const float* __restrict__ W3,
                                                 const float* __restrict__ b3,
                                                 float* __restrict__ ws) {
    __shared__ float W3s[64 * CAT];
    __shared__ float b3s[64];
    __shared__ float ps[128];
    int tid = threadIdx.x;
    for (int j = tid; j < 64 * CAT; j += 256) W3s[j] = W3[j];
    if (tid < 64) b3s[tid] = b3[tid];
    if (tid < 128) ps[tid] = 0.f;
    __syncthreads();
    int c = tid & 63, g = tid >> 6;
    const float* pool = ws + WS_POOL;
    float sum = 0.f, sq = 0.f;
    for (int m = 0; m < 64; m++) {
        int pt = blockIdx.x * 256 + g * 64 + m;
        const float* row = pool + (size_t)pt * CAT;
        float y = b3s[c];
        for (int j = 0; j < CAT; j++) y = fmaf(W3s[c * CAT + j], row[j], y);
        sum += y; sq = fmaf(y, y, sq);
    }
    atomicAdd(&ps[c], sum);
    atomicAdd(&ps[64 + c], sq);
    __syncthreads();
    if (tid < 128) atomicAdd(ws + WS_RED2 + tid, ps[tid]);
}

// ---------------- K7: derive BN2 scale/shift ----------------
__global__ void k7_prep2(const float* __restrict__ g2, const float* __restrict__ be2,
                         float* __restrict__ ws) {
    int c = threadIdx.x;
    if (c >= 64) return;
    float inv = 1.f / (float)M2;
    float mean = ws[WS_RED2 + c] * inv;
    float var = ws[WS_RED2 + 64 + c] * inv - mean * mean;
    float a = g2[c] * rsqrtf(var + EPSB);
    ws[WS_A2C2 + c] = a;
    ws[WS_A2C2 + 64 + c] = be2[c] - mean * a;
}

// ---------------- K8: out = conv4(relu(bn2(conv3(pooled)))) — h[64] only ----------------
__global__ __launch_bounds__(256) void k8_out(const float* __restrict__ W3,
                                              const float* __restrict__ b3,
                                              const float* __restrict__ W4,
                                              const float* __restrict__ b4,
                                              const float* __restrict__ ws,
                                              float* __restrict__ out) {
    __shared__ float W3t[CAT * 64];      // transposed: [j][o]
    __shared__ float W4s[64 * 64], b3s[64], b4s[64], ab[128];
    int tid = threadIdx.x;
    for (int lin = tid; lin < CAT * 64; lin += 256) {
        int j = lin >> 6, o = lin & 63;
        W3t[lin] = W3[o * CAT + j];
    }
    for (int j = tid; j < 4096; j += 256) W4s[j] = W4[j];
    if (tid < 64) { b3s[tid] = b3[tid]; b4s[tid] = b4[tid]; }
    if (tid < 128) ab[tid] = ws[WS_A2C2 + tid];
    __syncthreads();
    int pt = blockIdx.x * 256 + tid;
    const float* row = ws + WS_POOL + (size_t)pt * CAT;
    float h[64];
#pragma unroll
    for (int c = 0; c < 64; c++) h[c] = b3s[c];
    for (int j = 0; j < CAT; j++) {
        float pj = row[j];
#pragma unroll
        for (int c = 0; c < 64; c++) h[c] = fmaf(W3t[j * 64 + c], pj, h[c]);
    }
#pragma unroll
    for (int c = 0; c < 64; c++) h[c] = fmaxf(0.f, fmaf(ab[c], h[c], ab[64 + c]));
    float* op = out + (size_t)pt * 64;
    for (int o = 0; o < 64; o += 4) {
        float a0 = b4s[o], a1v = b4s[o + 1], a2v = b4s[o + 2], a3v = b4s[o + 3];
#pragma unroll
        for (int c = 0; c < 64; c++) {
            float hv = h[c];
            a0  = fmaf(W4s[(o)     * 64 + c], hv, a0);
            a1v = fmaf(W4s[(o + 1) * 64 + c], hv, a1v);
            a2v = fmaf(W4s[(o + 2) * 64 + c], hv, a2v);
            a3v = fmaf(W4s[(o + 3) * 64 + c], hv, a3v);
        }
        *(float4*)(op + o) = make_float4(a0, a1v, a2v, a3v);
    }
}

extern "C" void kernel_launch(void* const* d_in, const int* in_sizes, int n_in,
                              void* d_out, int out_size, void* d_ws, size_t ws_size,
                              hipStream_t stream) {
    (void)in_sizes; (void)n_in; (void)out_size; (void)ws_size;
    const float* xin = (const float*)d_in[0];
    const float* W1  = (const float*)d_in[1];
    const float* b1  = (const float*)d_in[2];
    const float* g1  = (const float*)d_in[3];
    const float* be1 = (const float*)d_in[4];
    const float* W2  = (const float*)d_in[5];
    const float* b2  = (const float*)d_in[6];
    const float* W3  = (const float*)d_in[7];
    const float* b3  = (const float*)d_in[8];
    const float* g2  = (const float*)d_in[9];
    const float* be2 = (const float*)d_in[10];
    const float* W4  = (const float*)d_in[11];
    const float* b4  = (const float*)d_in[12];
    float* ws = (float*)d_ws;
    float* out = (float*)d_out;

    hipMemsetAsync(d_ws, 0, (WS_RED2 + 128) * sizeof(float), stream);
    hipLaunchKernelGGL(k1_stats,  dim3(64),  dim3(256), 0, stream, xin, ws);
    hipLaunchKernelGGL(k2_prep,   dim3(1),   dim3(32),  0, stream, W1, b1, g1, be1, ws);
    hipLaunchKernelGGL(k3_feats,  dim3(128), dim3(256), 0, stream, xin, W1, b1, W2, b2, ws);
    hipLaunchKernelGGL(k4_fps,    dim3(8),   dim3(512), 0, stream, xin, ws);
    hipLaunchKernelGGL(k5_group,  dim3(256), dim3(256), 0, stream, xin, ws);
    hipLaunchKernelGGL(k6_stats2, dim3(64),  dim3(256), 0, stream, W3, b3, ws);
    hipLaunchKernelGGL(k7_prep2,  dim3(1),   dim3(64),  0, stream, g2, be2, ws);
    hipLaunchKernelGGL(k8_out,    dim3(64),  dim3(256), 0, stream, W3, b3, W4, b4, ws, out);
}

// Round 3
// 2758.865 us; speedup vs baseline: 1.9936x; 1.5151x over previous
//
#include <hip/hip_runtime.h>
#include <float.h>

#define BB   8
#define NN   4096
#define SS   2048
#define KK   16
#define MID  32
#define COUT 64
#define CAT  67            // 3 + 64
#define M1   (BB*NN)       // 32768
#define M2   (BB*SS)       // 16384
#define EPSB 1e-5f

// ---- workspace layout (float offsets) ----
#define WS_RED1  0                       // 12 floats  (Sx[3], C[6])
#define WS_RED2  16                      // 128 floats (sum[64], sumsq[64])
#define WS_A1C1  160                     // 64 floats
#define WS_A2C2  256                     // 128 floats
#define WS_FPS   512                     // 16384 ints
#define WS_FEATS (512 + 16384)           // 32768*64 floats
#define WS_POOL  (WS_FEATS + M1*COUT)    // 16384*67 floats

// ---------------- K1: input moments for BN1 stats ----------------
__global__ __launch_bounds__(256) void k1_stats(const float* __restrict__ xin,
                                                float* __restrict__ ws) {
    int t = blockIdx.x * 256 + threadIdx.x;
    float r[9];
#pragma unroll
    for (int q = 0; q < 9; q++) r[q] = 0.f;
    for (int p = t; p < M1; p += 64 * 256) {
        float x0 = xin[3 * p], x1 = xin[3 * p + 1], x2 = xin[3 * p + 2];
        r[0] += x0; r[1] += x1; r[2] += x2;
        r[3] = fmaf(x0, x0, r[3]); r[4] = fmaf(x0, x1, r[4]); r[5] = fmaf(x0, x2, r[5]);
        r[6] = fmaf(x1, x1, r[6]); r[7] = fmaf(x1, x2, r[7]); r[8] = fmaf(x2, x2, r[8]);
    }
#pragma unroll
    for (int m = 32; m; m >>= 1) {
#pragma unroll
        for (int q = 0; q < 9; q++) r[q] += __shfl_down(r[q], m, 64);
    }
    if ((threadIdx.x & 63) == 0) {
#pragma unroll
        for (int q = 0; q < 9; q++) atomicAdd(ws + WS_RED1 + q, r[q]);
    }
}

// ---------------- K2: derive BN1 scale/shift per channel ----------------
__global__ void k2_prep(const float* __restrict__ W1, const float* __restrict__ b1,
                        const float* __restrict__ g1, const float* __restrict__ be1,
                        float* __restrict__ ws) {
    int o = threadIdx.x;
    if (o >= MID) return;
    const float* r = ws + WS_RED1;
    float S0 = r[0], S1 = r[1], S2 = r[2];
    float C00 = r[3], C01 = r[4], C02 = r[5], C11 = r[6], C12 = r[7], C22 = r[8];
    float w0 = W1[3 * o], w1 = W1[3 * o + 1], w2 = W1[3 * o + 2];
    float invM = 1.f / (float)M1;
    float wS = w0 * S0 + w1 * S1 + w2 * S2;
    float mean = wS * invM + b1[o];
    float wCw = w0 * w0 * C00 + w1 * w1 * C11 + w2 * w2 * C22 +
                2.f * (w0 * w1 * C01 + w0 * w2 * C02 + w1 * w2 * C12);
    float ey2 = (wCw + 2.f * b1[o] * wS) * invM + b1[o] * b1[o];
    float var = ey2 - mean * mean;
    float a = g1[o] * rsqrtf(var + EPSB);
    ws[WS_A1C1 + o] = a;
    ws[WS_A1C1 + MID + o] = be1[o] - mean * a;
}

// ---------------- K3: feats = conv2(relu(bn(conv1(x)))) ----------------
__global__ __launch_bounds__(256) void k3_feats(const float* __restrict__ xin,
                                                const float* __restrict__ W1,
                                                const float* __restrict__ b1,
                                                const float* __restrict__ W2,
                                                const float* __restrict__ b2,
                                                float* __restrict__ ws) {
    __shared__ float W1s[96], b1s[32], abv[64], W2s[2048], b2s[64];
    int tid = threadIdx.x;
    for (int j = tid; j < 96; j += 256) W1s[j] = W1[j];
    if (tid < 32) b1s[tid] = b1[tid];
    if (tid < 64) { abv[tid] = ws[WS_A1C1 + tid]; b2s[tid] = b2[tid]; }
    for (int j = tid; j < 2048; j += 256) W2s[j] = W2[j];
    __syncthreads();
    int p = blockIdx.x * 256 + tid;
    float x0 = xin[3 * p], x1 = xin[3 * p + 1], x2 = xin[3 * p + 2];
    float h[MID];
#pragma unroll
    for (int o = 0; o < MID; o++) {
        float y = fmaf(W1s[3 * o + 2], x2, fmaf(W1s[3 * o + 1], x1, fmaf(W1s[3 * o], x0, b1s[o])));
        h[o] = fmaxf(0.f, fmaf(abv[o], y, abv[MID + o]));
    }
    float* fo = ws + WS_FEATS + (size_t)p * COUT;
#pragma unroll
    for (int j = 0; j < COUT; j += 4) {
        float a0 = b2s[j], a1v = b2s[j + 1], a2v = b2s[j + 2], a3v = b2s[j + 3];
#pragma unroll
        for (int o = 0; o < MID; o++) {
            float hv = h[o];
            a0  = fmaf(W2s[(j)     * MID + o], hv, a0);
            a1v = fmaf(W2s[(j + 1) * MID + o], hv, a1v);
            a2v = fmaf(W2s[(j + 2) * MID + o], hv, a2v);
            a3v = fmaf(W2s[(j + 3) * MID + o], hv, a3v);
        }
        *(float4*)(fo + j) = make_float4(a0, a1v, a2v, a3v);
    }
}

// ---------------- K4: FPS — packed u64 argmax, DPP reduce ----------------
__device__ __forceinline__ unsigned long long u64max(unsigned long long a,
                                                     unsigned long long b) {
    return a > b ? a : b;
}

template <int CTRL>
__device__ __forceinline__ unsigned long long dpp_swap_max(unsigned long long v) {
    int lo = (int)(unsigned)v;
    int hi = (int)(unsigned)(v >> 32);
    int olo = __builtin_amdgcn_update_dpp(0, lo, CTRL, 0xF, 0xF, false);
    int ohi = __builtin_amdgcn_update_dpp(0, hi, CTRL, 0xF, 0xF, false);
    unsigned long long ov = ((unsigned long long)(unsigned)ohi << 32) | (unsigned)olo;
    return u64max(v, ov);
}

__global__ __launch_bounds__(512) void k4_fps(const float* __restrict__ xin,
                                              float* __restrict__ ws) {
    __shared__ float4 Pc[NN];       // 64 KB (centroid broadcast lookup)
    __shared__ __align__(16) unsigned long long svbuf[2][8];
    int b = blockIdx.x, tid = threadIdx.x;
    const float* xb = xin + (size_t)b * NN * 3;
    float px[8], py[8], pz[8], dist[8];
#pragma unroll
    for (int k = 0; k < 8; k++) {
        int i = tid + (k << 9);
        float x = xb[3 * i], y = xb[3 * i + 1], z = xb[3 * i + 2];
        px[k] = x; py[k] = y; pz[k] = z; dist[k] = FLT_MAX;
        Pc[i] = make_float4(x, y, z, 0.f);
    }
    int* fidx = (int*)(ws + WS_FPS) + b * SS;
    if (tid == 0) fidx[0] = 0;
    __syncthreads();
    float4 c0 = Pc[0];
    float cx = c0.x, cy = c0.y, cz = c0.z;
    int wid = tid >> 6, lane = tid & 63;
    int a16 = ((lane ^ 16) << 2), a32 = ((lane ^ 32) << 2), a48 = ((lane ^ 48) << 2);
    for (int t = 1; t < SS; t++) {
        float bv = -1.f; int bi = 0;
#pragma unroll
        for (int k = 0; k < 8; k++) {
            float dx = px[k] - cx, dy = py[k] - cy, dz = pz[k] - cz;
            float d = fmaf(dz, dz, fmaf(dy, dy, dx * dx));
            float nd = fminf(dist[k], d);
            dist[k] = nd;
            bool bt = nd > bv;              // strict > + ascending k => lowest idx wins
            bv = bt ? nd : bv; bi = bt ? (tid + (k << 9)) : bi;
        }
        // pack: dist (>=0) in high 32, ~idx low => u64 max == lexicographic argmax
        unsigned long long v =
            ((unsigned long long)__float_as_uint(bv) << 32) | (unsigned)(~bi);
        v = dpp_swap_max<0xB1>(v);      // quad_perm xor1
        v = dpp_swap_max<0x4E>(v);      // quad_perm xor2
        v = dpp_swap_max<0x141>(v);     // row_half_mirror (xor-ish within 8)
        v = dpp_swap_max<0x140>(v);     // row_mirror (within 16)
        {   // cross-row: fetch the other three 16-lane rows in parallel
            int lo = (int)(unsigned)v, hi = (int)(unsigned)(v >> 32);
            int lo16 = __builtin_amdgcn_ds_bpermute(a16, lo);
            int hi16 = __builtin_amdgcn_ds_bpermute(a16, hi);
            int lo32 = __builtin_amdgcn_ds_bpermute(a32, lo);
            int hi32 = __builtin_amdgcn_ds_bpermute(a32, hi);
            int lo48 = __builtin_amdgcn_ds_bpermute(a48, lo);
            int hi48 = __builtin_amdgcn_ds_bpermute(a48, hi);
            unsigned long long v16 = ((unsigned long long)(unsigned)hi16 << 32) | (unsigned)lo16;
            unsigned long long v32 = ((unsigned long long)(unsigned)hi32 << 32) | (unsigned)lo32;
            unsigned long long v48 = ((unsigned long long)(unsigned)hi48 << 32) | (unsigned)lo48;
            v = u64max(u64max(v, v16), u64max(v32, v48));
        }
        int par = t & 1;
        if (lane == 0) svbuf[par][wid] = v;
        __syncthreads();
        const ulonglong2* sp = (const ulonglong2*)svbuf[par];
        ulonglong2 q0 = sp[0], q1 = sp[1], q2 = sp[2], q3 = sp[3];
        unsigned long long m0 = u64max(q0.x, q0.y), m1 = u64max(q1.x, q1.y);
        unsigned long long m2 = u64max(q2.x, q2.y), m3 = u64max(q3.x, q3.y);
        unsigned long long best = u64max(u64max(m0, m1), u64max(m2, m3));
        int bsel = (int)(~(unsigned)best);
        float4 cc = Pc[bsel];
        cx = cc.x; cy = cc.y; cz = cc.z;
        if (tid == 0) fidx[t] = bsel;
    }
}

// ---------------- K5: 16-NN + group + maxpool (4 lanes per centroid) ----------------
__global__ __launch_bounds__(256) void k5_group(const float* __restrict__ xin,
                                                float* __restrict__ ws) {
    __shared__ float4 Pq[NN];            // 64 KB: x,y,z,|p|^2
    __shared__ float2 cand[64][65];      // 33.3 KB (pad 65 to break bank stride)
    __shared__ int    fin[64][16];       // 4 KB
    int blk = blockIdx.x, tid = threadIdx.x;
    int b = blk >> 5;                    // 32 blocks per batch
    const float* xb = xin + (size_t)b * NN * 3;
    for (int j = tid; j < NN; j += 256) {
        float x = xb[3 * j], y = xb[3 * j + 1], z = xb[3 * j + 2];
        Pq[j] = make_float4(x, y, z, (x * x + y * y) + z * z);
    }
    __syncthreads();
    int cl = tid >> 2, q = tid & 3;
    int sg = blk * 64 + cl;              // global centroid id
    const int* fidx = (const int*)(ws + WS_FPS);
    int ci = fidx[sg];
    float4 c = Pq[ci];
    float an = c.w;
    float dv[16]; int di[16];
#pragma unroll
    for (int j = 0; j < 16; j++) { dv[j] = FLT_MAX; di[j] = 0x7fffffff; }
    float cmax = FLT_MAX; int cpos = 0, cidx = 0x7fffffff;
    int nbase = q << 10;
    for (int n0 = 0; n0 < 1024; n0++) {
        int n = nbase + n0;
        float4 qq = Pq[n];
        float dot = fmaf(c.z, qq.z, fmaf(c.y, qq.y, c.x * qq.x));
        float dd = (an + qq.w) - 2.f * dot;
        if (dd < cmax) {                 // ascending n within chunk => strict < exact
#pragma unroll
            for (int j = 0; j < 16; j++) {
                bool sel = (j == cpos);
                dv[j] = sel ? dd : dv[j];
                di[j] = sel ? n : di[j];
            }
            cmax = dv[0]; cidx = di[0]; cpos = 0;
#pragma unroll
            for (int j = 1; j < 16; j++) {
                bool bt = (dv[j] > cmax) || ((dv[j] == cmax) && (di[j] > cidx));
                cmax = bt ? dv[j] : cmax; cidx = bt ? di[j] : cidx; cpos = bt ? j : cpos;
            }
        }
    }
#pragma unroll
    for (int j = 0; j < 16; j++)
        cand[cl][q * 16 + j] = make_float2(dv[j], __int_as_float(di[j]));
    __syncthreads();
    if (tid < 64) {                      // phase 2: merge 64 -> 16
        float mv[16]; int mi[16];
#pragma unroll
        for (int j = 0; j < 16; j++) { mv[j] = FLT_MAX; mi[j] = 0x7fffffff; }
        float mx = FLT_MAX; int mp = 0, mxi = 0x7fffffff;
        for (int k = 0; k < 64; k++) {
            float2 e = cand[tid][k];
            float d = e.x; int i = __float_as_int(e.y);
            if (d < mx || (d == mx && i < mxi)) {   // lexicographic entry test
#pragma unroll
                for (int j = 0; j < 16; j++) {
                    bool sel = (j == mp);
                    mv[j] = sel ? d : mv[j];
                    mi[j] = sel ? i : mi[j];
                }
                mx = mv[0]; mxi = mi[0]; mp = 0;
#pragma unroll
                for (int j = 1; j < 16; j++) {
                    bool bt = (mv[j] > mx) || ((mv[j] == mx) && (mi[j] > mxi));
                    mx = bt ? mv[j] : mx; mxi = bt ? mi[j] : mxi; mp = bt ? j : mp;
                }
            }
        }
#pragma unroll
        for (int j = 0; j < 16; j++) fin[tid][j] = mi[j];
    }
    __syncthreads();
    // phase 3: pooling — lane q handles 16 of the 64 feat channels
    int idxs[16];
#pragma unroll
    for (int j = 0; j < 16; j++) idxs[j] = fin[cl][j];
    const float* feats = ws + WS_FEATS + (size_t)b * NN * COUT;
    float4 acc[4];
#pragma unroll
    for (int m = 0; m < 4; m++) acc[m] = make_float4(-FLT_MAX, -FLT_MAX, -FLT_MAX, -FLT_MAX);
#pragma unroll 4
    for (int k = 0; k < 16; k++) {
        const float4* fp = (const float4*)(feats + (size_t)idxs[k] * COUT) + q * 4;
#pragma unroll
        for (int m = 0; m < 4; m++) {
            float4 v = fp[m];
            acc[m].x = fmaxf(acc[m].x, v.x); acc[m].y = fmaxf(acc[m].y, v.y);
            acc[m].z = fmaxf(acc[m].z, v.z); acc[m].w = fmaxf(acc[m].w, v.w);
        }
    }
    float* po = ws + WS_POOL + (size_t)sg * CAT;
#pragma unroll
    for (int m = 0; m < 4; m++) {
        int base = 3 + q * 16 + m * 4;
        po[base] = acc[m].x; po[base + 1] = acc[m].y;
        po[base + 2] = acc[m].z; po[base + 3] = acc[m].w;
    }
    if (q == 0) {
        float rx = -FLT_MAX, ry = -FLT_MAX, rz = -FLT_MAX;
#pragma unroll
        for (int k = 0; k < 16; k++) {
            float4 p = Pq[idxs[k]];
            rx = fmaxf(rx, p.x - c.x); ry = fmaxf(ry, p.y - c.y); rz = fmaxf(rz, p.z - c.z);
        }
        po[0] = rx; po[1] = ry; po[2] = rz;
    }
}

// ---------------- K6: BN2 stats over conv3 output ----------------
__global__ __launch_bounds__(256) void k6_stats2(const float* __restrict__ W3,
                                                 const float* __restrict__ b3,
                                                 float* __restrict__ ws) {
    __shared__ float W3s[64 * CAT];
    __shared__ float b3s[64];
    __shared__ float ps[128];
    int tid = threadIdx.x;
    for (int j = tid; j < 64 * CAT; j += 256) W3s[j] = W3[j];
    if (tid < 64) b3s[tid] = b3[tid];
    if (tid < 128) ps[tid] = 0.f;
    __syncthreads();
    int c = tid & 63, g = tid >> 6;
    const float* pool = ws + WS_POOL;
    float sum = 0.f, sq = 0.f;
    for (int m = 0; m < 64; m++) {
        int pt = blockIdx.x * 256 + g * 64 + m;
        const float* row = pool + (size_t)pt * CAT;
        float y = b3s[c];
        for (int j = 0; j < CAT; j++) y = fmaf(W3s[c * CAT + j], row[j], y);
        sum += y; sq = fmaf(y, y, sq);
    }
    atomicAdd(&ps[c], sum);
    atomicAdd(&ps[64 + c], sq);
    __syncthreads();
    if (tid < 128) atomicAdd(ws + WS_RED2 + tid, ps[tid]);
}

// ---------------- K7: derive BN2 scale/shift ----------------
__global__ void k7_prep2(const float* __restrict__ g2, const float* __restrict__ be2,
                         float* __restrict__ ws) {
    int c = threadIdx.x;
    if (c >= 64) return;
    float inv = 1.f / (float)M2;
    float mean = ws[WS_RED2 + c] * inv;
    float var = ws[WS_RED2 + 64 + c] * inv - mean * mean;
    float a = g2[c] * rsqrtf(var + EPSB);
    ws[WS_A2C2 + c] = a;
    ws[WS_A2C2 + 64 + c] = be2[c] - mean * a;
}

// ---------------- K8: out = conv4(relu(bn2(conv3(pooled)))) — h[64] only ----------------
__global__ __launch_bounds__(256) void k8_out(const float* __restrict__ W3,
                                              const float* __restrict__ b3,
                                              const float* __restrict__ W4,
                                              const float* __restrict__ b4,
                                              const float* __restrict__ ws,
                                              float* __restrict__ out) {
    __shared__ float W3t[CAT * 64];      // transposed: [j][o]
    __shared__ float W4s[64 * 64], b3s[64], b4s[64], ab[128];
    int tid = threadIdx.x;
    for (int lin = tid; lin < CAT * 64; lin += 256) {
        int j = lin >> 6, o = lin & 63;
        W3t[lin] = W3[o * CAT + j];
    }
    for (int j = tid; j < 4096; j += 256) W4s[j] = W4[j];
    if (tid < 64) { b3s[tid] = b3[tid]; b4s[tid] = b4[tid]; }
    if (tid < 128) ab[tid] = ws[WS_A2C2 + tid];
    __syncthreads();
    int pt = blockIdx.x * 256 + tid;
    const float* row = ws + WS_POOL + (size_t)pt * CAT;
    float h[64];
#pragma unroll
    for (int c = 0; c < 64; c++) h[c] = b3s[c];
    for (int j = 0; j < CAT; j++) {
        float pj = row[j];
#pragma unroll
        for (int c = 0; c < 64; c++) h[c] = fmaf(W3t[j * 64 + c], pj, h[c]);
    }
#pragma unroll
    for (int c = 0; c < 64; c++) h[c] = fmaxf(0.f, fmaf(ab[c], h[c], ab[64 + c]));
    float* op = out + (size_t)pt * 64;
    for (int o = 0; o < 64; o += 4) {
        float a0 = b4s[o], a1v = b4s[o + 1], a2v = b4s[o + 2], a3v = b4s[o + 3];
#pragma unroll
        for (int c = 0; c < 64; c++) {
            float hv = h[c];
            a0  = fmaf(W4s[(o)     * 64 + c], hv, a0);
            a1v = fmaf(W4s[(o + 1) * 64 + c], hv, a1v);
            a2v = fmaf(W4s[(o + 2) * 64 + c], hv, a2v);
            a3v = fmaf(W4s[(o + 3) * 64 + c], hv, a3v);
        }
        *(float4*)(op + o) = make_float4(a0, a1v, a2v, a3v);
    }
}

extern "C" void kernel_launch(void* const* d_in, const int* in_sizes, int n_in,
                              void* d_out, int out_size, void* d_ws, size_t ws_size,
                              hipStream_t stream) {
    (void)in_sizes; (void)n_in; (void)out_size; (void)ws_size;
    const float* xin = (const float*)d_in[0];
    const float* W1  = (const float*)d_in[1];
    const float* b1  = (const float*)d_in[2];
    const float* g1  = (const float*)d_in[3];
    const float* be1 = (const float*)d_in[4];
    const float* W2  = (const float*)d_in[5];
    const float* b2  = (const float*)d_in[6];
    const float* W3  = (const float*)d_in[7];
    const float* b3  = (const float*)d_in[8];
    const float* g2  = (const float*)d_in[9];
    const float* be2 = (const float*)d_in[10];
    const float* W4  = (const float*)d_in[11];
    const float* b4  = (const float*)d_in[12];
    float* ws = (float*)d_ws;
    float* out = (float*)d_out;

    hipMemsetAsync(d_ws, 0, (WS_RED2 + 128) * sizeof(float), stream);
    hipLaunchKernelGGL(k1_stats,  dim3(64),  dim3(256), 0, stream, xin, ws);
    hipLaunchKernelGGL(k2_prep,   dim3(1),   dim3(32),  0, stream, W1, b1, g1, be1, ws);
    hipLaunchKernelGGL(k3_feats,  dim3(128), dim3(256), 0, stream, xin, W1, b1, W2, b2, ws);
    hipLaunchKernelGGL(k4_fps,    dim3(8),   dim3(512), 0, stream, xin, ws);
    hipLaunchKernelGGL(k5_group,  dim3(256), dim3(256), 0, stream, xin, ws);
    hipLaunchKernelGGL(k6_stats2, dim3(64),  dim3(256), 0, stream, W3, b3, ws);
    hipLaunchKernelGGL(k7_prep2,  dim3(1),   dim3(64),  0, stream, g2, be2, ws);
    hipLaunchKernelGGL(k8_out,    dim3(64),  dim3(256), 0, stream, W3, b3, W4, b4, ws, out);
}